// Round 18
// baseline (149.251 us; speedup 1.0000x reference)
//
#include <hip/hip_runtime.h>
#include <hip/hip_bf16.h>

// Fused WindowAttention: x @ W_qkv + b -> MHA(16 heads, D=64) -> @ W_proj + b
// B=8, N=1024, C=1024. fp32 in/out; internal bf16 MFMA + fp32 accum.
//
// Pipeline (4 kernels), per-kernel best measured config:
//   1. prep: X f32->bf16  +  W_qkv^T -> Wqt bf16  +  W_proj^T -> Wpt bf16
//   2. qkv_gemm2: single-buffer 2-phase, BK=64, swizzled (33.3KB LDS; best)
//   3. attn_kernel (r15 form: 8 waves x 256 q-rows)
//   4. proj_gemm2: double-buffered counted-vmcnt (64KB LDS; best)

using bf16x8 = __attribute__((ext_vector_type(8))) short;
using f32x4  = __attribute__((ext_vector_type(4))) float;
using u16    = unsigned short;
using u16x8  = __attribute__((ext_vector_type(8))) unsigned short;
using u32x2  = __attribute__((ext_vector_type(2))) unsigned int;

__device__ __forceinline__ u16 f2bf(float f) {
  unsigned int u = __float_as_uint(f);
  u += 0x7FFFu + ((u >> 16) & 1u);   // RNE (finite inputs only)
  return (u16)(u >> 16);
}
__device__ __forceinline__ float bf2f(u16 h) {
  return __uint_as_float(((unsigned int)h) << 16);
}
__device__ __forceinline__ unsigned cvt_pk_bf16(float a, float b) {
  unsigned r;
  asm("v_cvt_pk_bf16_f32 %0, %1, %2" : "=v"(r) : "v"(a), "v"(b));
  return r;
}
__device__ __forceinline__ float fexp2(float x) {
#if __has_builtin(__builtin_amdgcn_exp2f)
  return __builtin_amdgcn_exp2f(x);
#else
  return exp2f(x);
#endif
}

__device__ __forceinline__ void gload16(const u16* g, u16* lbase, int lane) {
#if __has_builtin(__builtin_amdgcn_global_load_lds)
  __builtin_amdgcn_global_load_lds(
      (const __attribute__((address_space(1))) void*)g,
      (__attribute__((address_space(3))) void*)lbase, 16, 0, 0);
#else
  *(u16x8*)(lbase + (size_t)lane * 8) = *(const u16x8*)g;
#endif
}

// ---------------------------------------------------------------------------
// prep: block-range union {f32->bf16 convert, W_qkv^T, W_proj^T}.
// ---------------------------------------------------------------------------
__device__ __forceinline__ void transpose_tile(
    const float* __restrict__ W, u16* __restrict__ Wt, int K, int N,
    int n0, int k0, float (*T)[65], int t)
{
  const int r = t >> 4, c4 = (t & 15) * 4;
  #pragma unroll
  for (int i = 0; i < 4; ++i) {
    f32x4 v = *(const f32x4*)&W[(size_t)(k0 + r + i * 16) * N + n0 + c4];
    T[r + i * 16][c4 + 0] = v.x;
    T[r + i * 16][c4 + 1] = v.y;
    T[r + i * 16][c4 + 2] = v.z;
    T[r + i * 16][c4 + 3] = v.w;
  }
  __syncthreads();
  const int nr = t >> 2, cs = (t & 3) * 16;
  u16x8 h0, h1;
  #pragma unroll
  for (int j = 0; j < 8; ++j) h0[j] = f2bf(T[cs + j][nr]);
  #pragma unroll
  for (int j = 0; j < 8; ++j) h1[j] = f2bf(T[cs + 8 + j][nr]);
  u16* dst = Wt + (size_t)(n0 + nr) * K + k0 + cs;
  *(u16x8*)dst = h0;
  *(u16x8*)(dst + 8) = h1;
}

__global__ __launch_bounds__(256) void prep(
    const float* __restrict__ x, u16* __restrict__ Xb,
    const float* __restrict__ Wq, u16* __restrict__ Wqt,
    const float* __restrict__ Wp, u16* __restrict__ Wpt)
{
  __shared__ float T[64][65];
  const int bid = blockIdx.x, t = threadIdx.x;
  if (bid < 4096) {
    size_t i = ((size_t)bid * 256 + t) * 8;
    f32x4 a = *(const f32x4*)(x + i);
    f32x4 b = *(const f32x4*)(x + i + 4);
    u16x8 h = { f2bf(a.x), f2bf(a.y), f2bf(a.z), f2bf(a.w),
                f2bf(b.x), f2bf(b.y), f2bf(b.z), f2bf(b.w) };
    *(u16x8*)(Xb + i) = h;
  } else if (bid < 4864) {
    const int tb = bid - 4096;
    transpose_tile(Wq, Wqt, 1024, 3072, (tb % 48) * 64, (tb / 48) * 64, T, t);
  } else {
    const int tb = bid - 4864;
    transpose_tile(Wp, Wpt, 1024, 1024, (tb % 16) * 64, (tb / 16) * 64, T, t);
  }
}

// ---------------------------------------------------------------------------
// Single-buffer GEMM main loop (qkv best): 128x128, 4 waves, BK=64.
// ---------------------------------------------------------------------------
#define GEMM64_LOOP(ABASE, BBASE, AS, BS)                                     \
  const int tid = threadIdx.x;                                                \
  const int lane = tid & 63, wid = tid >> 6;                                  \
  const int wr = wid >> 1, wc = wid & 1;                                      \
  const int lg = lane >> 4, lc = lane & 15;                                   \
  const int row0 = blockIdx.x * 128, col0 = blockIdx.y * 128;                 \
  f32x4 acc[4][4];                                                            \
  _Pragma("unroll")                                                           \
  for (int m = 0; m < 4; ++m)                                                 \
    _Pragma("unroll")                                                         \
    for (int n = 0; n < 4; ++n) acc[m][n] = (f32x4){0.f, 0.f, 0.f, 0.f};      \
  const int srow = lane >> 3;                /* 0..7 */                       \
  const int sslot = (lane & 7) ^ srow;       /* pre-swizzled 16B slot */      \
  const u16* gA = (ABASE) + (size_t)(row0 + wid * 32 + srow) * 1024 + sslot * 8; \
  const u16* gB = (BBASE) + (size_t)(col0 + wid * 32 + srow) * 1024 + sslot * 8; \
  u16* lA = (AS) + wid * 2048;                                                \
  u16* lB = (BS) + wid * 2048;                                                \
  const int xr = lc & 7;                                                      \
  const int sl0 = ((0 + lg) ^ xr) * 8, sl1 = ((4 + lg) ^ xr) * 8;             \
  const int arow = (wr * 64 + lc) * 64, brow = (wc * 64 + lc) * 64;           \
  for (int k0 = 0; k0 < 1024; k0 += 64) {                                     \
    _Pragma("unroll")                                                         \
    for (int c = 0; c < 4; ++c) {                                             \
      gload16(gA + (size_t)c * 8192 + k0, lA + c * 512, lane);                \
      gload16(gB + (size_t)c * 8192 + k0, lB + c * 512, lane);                \
    }                                                                         \
    __syncthreads();                                                          \
    _Pragma("unroll")                                                         \
    for (int ks = 0; ks < 2; ++ks) {                                          \
      const int sl = ks ? sl1 : sl0;                                          \
      bf16x8 a[4], b[4];                                                      \
      _Pragma("unroll")                                                       \
      for (int m = 0; m < 4; ++m)                                             \
        a[m] = *(const bf16x8*)((AS) + arow + m * 1024 + sl);                 \
      _Pragma("unroll")                                                       \
      for (int n = 0; n < 4; ++n)                                             \
        b[n] = *(const bf16x8*)((BS) + brow + n * 1024 + sl);                 \
      __builtin_amdgcn_s_setprio(1);                                          \
      _Pragma("unroll")                                                       \
      for (int m = 0; m < 4; ++m)                                             \
        _Pragma("unroll")                                                     \
        for (int n = 0; n < 4; ++n)                                           \
          acc[m][n] = __builtin_amdgcn_mfma_f32_16x16x32_bf16(                \
              a[m], b[n], acc[m][n], 0, 0, 0);                                \
      __builtin_amdgcn_s_setprio(0);                                          \
    }                                                                         \
    __syncthreads();                                                          \
  }

// ---------------------------------------------------------------------------
// Double-buffered GEMM main loop (proj best): counted vmcnt(8), raw barriers.
// ---------------------------------------------------------------------------
#define GEMM64_DBUF(ABASE, BBASE, AS, BS)                                     \
  const int tid = threadIdx.x;                                                \
  const int lane = tid & 63, wid = tid >> 6;                                  \
  const int wr = wid >> 1, wc = wid & 1;                                      \
  const int lg = lane >> 4, lc = lane & 15;                                   \
  const int row0 = blockIdx.x * 128, col0 = blockIdx.y * 128;                 \
  f32x4 acc[4][4];                                                            \
  _Pragma("unroll")                                                           \
  for (int m = 0; m < 4; ++m)                                                 \
    _Pragma("unroll")                                                         \
    for (int n = 0; n < 4; ++n) acc[m][n] = (f32x4){0.f, 0.f, 0.f, 0.f};      \
  const int srow = lane >> 3;                                                 \
  const int sslot = (lane & 7) ^ srow;                                        \
  const u16* gA = (ABASE) + (size_t)(row0 + wid * 32 + srow) * 1024 + sslot * 8; \
  const u16* gB = (BBASE) + (size_t)(col0 + wid * 32 + srow) * 1024 + sslot * 8; \
  u16* lA = (AS) + wid * 2048;                                                \
  u16* lB = (BS) + wid * 2048;                                                \
  auto STAGE = [&](int tt) {                                                  \
    const int bo = (tt & 1) * 8192, ko = tt * 64;                             \
    _Pragma("unroll")                                                         \
    for (int c = 0; c < 4; ++c) {                                             \
      gload16(gA + (size_t)c * 8192 + ko, lA + bo + c * 512, lane);           \
      gload16(gB + (size_t)c * 8192 + ko, lB + bo + c * 512, lane);           \
    }                                                                         \
  };                                                                          \
  STAGE(0);                                                                   \
  const int xr = lc & 7;                                                      \
  const int sl0 = ((0 + lg) ^ xr) * 8, sl1 = ((4 + lg) ^ xr) * 8;             \
  const int arow = (wr * 64 + lc) * 64, brow = (wc * 64 + lc) * 64;           \
  for (int t = 0; t < 16; ++t) {                                              \
    if (t < 15) {                                                             \
      STAGE(t + 1);                                                           \
      asm volatile("s_waitcnt vmcnt(8)" ::: "memory");                        \
    } else {                                                                  \
      asm volatile("s_waitcnt vmcnt(0)" ::: "memory");                        \
    }                                                                         \
    __builtin_amdgcn_s_barrier();                                             \
    const int bo = (t & 1) * 8192;                                            \
    _Pragma("unroll")                                                         \
    for (int ks = 0; ks < 2; ++ks) {                                          \
      const int sl = ks ? sl1 : sl0;                                          \
      bf16x8 a[4], b[4];                                                      \
      _Pragma("unroll")                                                       \
      for (int m = 0; m < 4; ++m)                                             \
        a[m] = *(const bf16x8*)((AS) + bo + arow + m * 1024 + sl);            \
      _Pragma("unroll")                                                       \
      for (int n = 0; n < 4; ++n)                                             \
        b[n] = *(const bf16x8*)((BS) + bo + brow + n * 1024 + sl);            \
      __builtin_amdgcn_s_setprio(1);                                          \
      _Pragma("unroll")                                                       \
      for (int m = 0; m < 4; ++m)                                             \
        _Pragma("unroll")                                                     \
        for (int n = 0; n < 4; ++n)                                           \
          acc[m][n] = __builtin_amdgcn_mfma_f32_16x16x32_bf16(                \
              a[m], b[n], acc[m][n], 0, 0, 0);                                \
      __builtin_amdgcn_s_setprio(0);                                          \
    }                                                                         \
    __builtin_amdgcn_s_barrier();                                             \
  }

// ---------------------------------------------------------------------------
// QKV GEMM (single-buffer). Q,K -> [bh][n][64] scalar scatter; V tile ->
// LDS transpose -> coalesced V^T. LDS union {As+Bs 32KB | Tv 33.3KB}.
// ---------------------------------------------------------------------------
__global__ __launch_bounds__(256, 2) void qkv_gemm2(
    const u16* __restrict__ Xb, const u16* __restrict__ Wt,
    const float* __restrict__ bias,
    u16* __restrict__ Qb, u16* __restrict__ Kb, u16* __restrict__ VtG)
{
  __shared__ __align__(16) u16 SM[128 * 130];   // 33.3 KB
  u16* As = SM;                // 128*64
  u16* Bs = SM + 8192;         // 128*64
  u16* Tv = SM;                // epilogue transpose buffer (union)

  GEMM64_LOOP(Xb, Wt, As, Bs)

  const int which = col0 >> 10;   // block-uniform: 0=Q, 1=K, 2=V
  if (which == 2) {
    #pragma unroll
    for (int m = 0; m < 4; ++m) {
      #pragma unroll
      for (int n = 0; n < 4; ++n) {
        const int col = wc * 64 + n * 16 + lc;
        const float bv = bias[col0 + col];
        const int rrow = wr * 64 + m * 16 + lg * 4;
        #pragma unroll
        for (int r = 0; r < 4; ++r)
          Tv[(rrow + r) * 130 + col] = f2bf(acc[m][n][r] + bv);
      }
    }
    __syncthreads();
    const int c = tid >> 1, half = tid & 1;
    const int hh = c >> 6, d = c & 63;
    const int bb = row0 >> 10, nb = row0 & 1023;
    const int hbase = (col0 & 1023) >> 6;
    u16* vdst = VtG + ((size_t)(bb * 16 + hbase + hh) * 64 + d) * 1024
                + nb + half * 64;
    #pragma unroll
    for (int g = 0; g < 8; ++g) {
      u16x8 o;
      #pragma unroll
      for (int j = 0; j < 8; ++j)
        o[j] = Tv[(half * 64 + g * 8 + j) * 130 + c];
      *(u16x8*)(vdst + g * 8) = o;
    }
  } else {
    u16* dst = (which == 0) ? Qb : Kb;
    #pragma unroll
    for (int m = 0; m < 4; ++m) {
      #pragma unroll
      for (int n = 0; n < 4; ++n) {
        const int gc = col0 + wc * 64 + n * 16 + lc;
        const float bv = bias[gc];
        const int ci = gc & 1023, h = ci >> 6, d = ci & 63;
        const int gr0 = row0 + wr * 64 + m * 16 + lg * 4;
        const int bb = gr0 >> 10, nn0 = gr0 & 1023;
        #pragma unroll
        for (int r = 0; r < 4; ++r)
          dst[((size_t)(bb * 16 + h) * 1024 + nn0 + r) * 64 + d] =
              f2bf(acc[m][n][r] + bv);
      }
    }
  }
}

// ---------------------------------------------------------------------------
// Flash attention (r15 form). Block = 256 q-rows of one (b,h); 8 waves x 32.
// ---------------------------------------------------------------------------
__global__ __launch_bounds__(512, 1) void attn_kernel(
    const u16* __restrict__ Q, const u16* __restrict__ K,
    const u16* __restrict__ Vt, u16* __restrict__ O)
{
  __shared__ __align__(16) u16 Ks[64 * 64];       // [key][d] swizzled, 8KB
  __shared__ __align__(16) u16 Vs[64 * 64];       // [d][key] swizzled, 8KB
  __shared__ __align__(16) u16 Pl[8 * 32 * 72];   // per-wave P, 36.9KB

  const int tid = threadIdx.x, lane = tid & 63, wid = tid >> 6;  // wid 0..7
  const int lg = lane >> 4, lc = lane & 15;
  const int bh = blockIdx.x;       // [0,128)
  const int qt = blockIdx.y;       // [0,4)
  const size_t base = (size_t)bh * 65536;
  const u16* Qp = Q + base;
  const u16* Kp = K + base;
  const u16* Vp = Vt + base;       // [64][1024]

  const float QSCALE = 0.125f * 1.44269504f;
  bf16x8 qf[2][2];
  #pragma unroll
  for (int f = 0; f < 2; ++f) {
    const u16* qsrc = Qp + (size_t)(qt * 256 + wid * 32 + f * 16 + lc) * 64 + lg * 8;
    #pragma unroll
    for (int ks = 0; ks < 2; ++ks) {
      u16x8 raw = *(const u16x8*)(qsrc + ks * 32);
      bf16x8 t;
      #pragma unroll
      for (int j = 0; j < 8; ++j) t[j] = (short)f2bf(bf2f(raw[j]) * QSCALE);
      qf[f][ks] = t;
    }
  }

  f32x4 o[2][4];
  #pragma unroll
  for (int f = 0; f < 2; ++f)
    #pragma unroll
    for (int d = 0; d < 4; ++d) o[f][d] = (f32x4){0.f, 0.f, 0.f, 0.f};
  float m_r[2] = {-1e30f, -1e30f};  // log2 domain
  float l_r[2] = {0.f, 0.f};        // per-lane partial row sums

  const int srow  = lane >> 3;               // 0..7
  const int sslot = (lane & 7) ^ srow;       // pre-swizzled 16B slot
  const u16* gK0 = Kp + (size_t)(wid * 8 + srow) * 64 + sslot * 8;
  const u16* gV0 = Vp + (size_t)(wid * 8 + srow) * 1024 + sslot * 8;
  u16* lK0 = Ks + wid * 512;
  u16* lV0 = Vs + wid * 512;

  const int xr = lc & 7;
  const int cof0 = ((0 + lg) ^ xr) * 8;
  const int cof1 = ((4 + lg) ^ xr) * 8;
  const int prow = (wid * 32 + lc) * 72;

  for (int kt = 0; kt < 16; ++kt) {
    gload16(gK0 + kt * 4096, lK0, lane);
    gload16(gV0 + kt * 64, lV0, lane);
    __syncthreads();

    f32x4 s[2][4];
    #pragma unroll
    for (int f = 0; f < 2; ++f)
      #pragma unroll
      for (int kb = 0; kb < 4; ++kb) s[f][kb] = (f32x4){0.f, 0.f, 0.f, 0.f};
    #pragma unroll
    for (int ks = 0; ks < 2; ++ks) {
      const int co = ks ? cof1 : cof0;
      #pragma unroll
      for (int kb = 0; kb < 4; ++kb) {
        bf16x8 kfr = *(const bf16x8*)(Ks + (kb * 16 + lc) * 64 + co);
        s[0][kb] = __builtin_amdgcn_mfma_f32_16x16x32_bf16(kfr, qf[0][ks], s[0][kb], 0, 0, 0);
        s[1][kb] = __builtin_amdgcn_mfma_f32_16x16x32_bf16(kfr, qf[1][ks], s[1][kb], 0, 0, 0);
      }
    }

    #pragma unroll
    for (int f = 0; f < 2; ++f) {
      f32x4 t01, t23;
      #pragma unroll
      for (int c = 0; c < 4; ++c) {
        t01[c] = fmaxf(s[f][0][c], s[f][1][c]);
        t23[c] = fmaxf(s[f][2][c], s[f][3][c]);
      }
      float t = fmaxf(fmaxf(fmaxf(t01[0], t01[1]), fmaxf(t01[2], t01[3])),
                      fmaxf(fmaxf(t23[0], t23[1]), fmaxf(t23[2], t23[3])));
      t = fmaxf(t, __shfl_xor(t, 16));
      t = fmaxf(t, __shfl_xor(t, 32));

      if (!__all((t - m_r[f]) <= 11.5f)) {          // max grew: rescale
        float nm = fmaxf(m_r[f], t);
        float sc = fexp2(m_r[f] - nm);
        m_r[f] = nm;
        l_r[f] *= sc;
        #pragma unroll
        for (int r = 0; r < 4; ++r) {
          float scr = __shfl(sc, lg * 4 + r, 16);
          #pragma unroll
          for (int d = 0; d < 4; ++d) o[f][d][r] *= scr;
        }
      }

      float lsum = 0.f;
      #pragma unroll
      for (int kb = 0; kb < 4; ++kb) {
        f32x4 p;
        #pragma unroll
        for (int c = 0; c < 4; ++c) {
          p[c] = fexp2(s[f][kb][c] - m_r[f]);
          lsum += p[c];
        }
        u32x2 w = { cvt_pk_bf16(p[0], p[1]), cvt_pk_bf16(p[2], p[3]) };
        *(u32x2*)(Pl + prow + f * 1152 + kb * 16 + lg * 4) = w;
      }
      l_r[f] += lsum;   // partial; cross-lane reduce in epilogue
    }

    asm volatile("s_waitcnt lgkmcnt(0)" ::: "memory");
    __builtin_amdgcn_sched_barrier(0);

    bf16x8 pa[2][2];
    #pragma unroll
    for (int f = 0; f < 2; ++f)
      #pragma unroll
      for (int ks = 0; ks < 2; ++ks)
        pa[f][ks] = *(const bf16x8*)(Pl + prow + f * 1152 + ks * 32 + lg * 8);
    #pragma unroll
    for (int d = 0; d < 4; ++d) {
      #pragma unroll
      for (int ks = 0; ks < 2; ++ks) {
        const int co = ks ? cof1 : cof0;
        bf16x8 vfr = *(const bf16x8*)(Vs + (d * 16 + lc) * 64 + co);
        o[0][d] = __builtin_amdgcn_mfma_f32_16x16x32_bf16(pa[0][ks], vfr, o[0][d], 0, 0, 0);
        o[1][d] = __builtin_amdgcn_mfma_f32_16x16x32_bf16(pa[1][ks], vfr, o[1][d], 0, 0, 0);
      }
    }
    __syncthreads();
  }

  const int b = bh >> 4, h = bh & 15;
  #pragma unroll
  for (int f = 0; f < 2; ++f) {
    float t = l_r[f];
    t += __shfl_xor(t, 16);
    t += __shfl_xor(t, 32);
    float linv = 1.0f / t;
    #pragma unroll
    for (int r = 0; r < 4; ++r) {
      float li = __shfl(linv, lg * 4 + r, 16);
      int n = qt * 256 + wid * 32 + f * 16 + lg * 4 + r;
      u16* dst = O + ((size_t)b * 1024 + n) * 1024 + h * 64 + lc;
      #pragma unroll
      for (int d = 0; d < 4; ++d) dst[d * 16] = f2bf(o[f][d][r] * li);
    }
  }
}

// ---------------------------------------------------------------------------
// Projection GEMM (dbuf structure — measured best for proj).
// ---------------------------------------------------------------------------
__global__ __launch_bounds__(256, 2) void proj_gemm2(
    const u16* __restrict__ Ab, const u16* __restrict__ Wt,
    const float* __restrict__ bias, float* __restrict__ Out)
{
  __shared__ __align__(16) u16 As[2 * 128 * 64];
  __shared__ __align__(16) u16 Bs[2 * 128 * 64];

  GEMM64_DBUF(Ab, Wt, As, Bs)

  #pragma unroll
  for (int m = 0; m < 4; ++m) {
    #pragma unroll
    for (int n = 0; n < 4; ++n) {
      #pragma unroll
      for (int r = 0; r < 4; ++r) {
        int gr = row0 + wr * 64 + m * 16 + lg * 4 + r;
        int gc = col0 + wc * 64 + n * 16 + lc;
        Out[(size_t)gr * 1024 + gc] = acc[m][n][r] + bias[gc];
      }
    }
  }
}

// ---------------------------------------------------------------------------
extern "C" void kernel_launch(void* const* d_in, const int* in_sizes, int n_in,
                              void* d_out, int out_size, void* d_ws, size_t ws_size,
                              hipStream_t stream) {
  const float* x     = (const float*)d_in[0];
  const float* W_qkv = (const float*)d_in[1];
  const float* b_qkv = (const float*)d_in[2];
  const float* W_prj = (const float*)d_in[3];
  const float* b_prj = (const float*)d_in[4];
  float* out = (float*)d_out;

  const size_t SEG = (size_t)8192 * 1024;   // 8388608 elems (u16)
  char* ws = (char*)d_ws;                   // needs ~42 MiB
  u16* Xb  = (u16*)ws;                      // dead after qkv
  u16* Ab  = Xb;                            // alias: attn output
  u16* VtG = (u16*)(ws + SEG * 2);          // V^T [bh][64][1024]
  u16* Wqt = (u16*)(ws + SEG * 4);
  u16* Wpt = Wqt + (size_t)3072 * 1024;
  u16* Qb  = (u16*)d_out;                   // d_out as scratch
  u16* Kb  = Qb + SEG;

  prep<<<5120, 256, 0, stream>>>(x, Xb, W_qkv, Wqt, W_prj, Wpt);
  qkv_gemm2<<<dim3(64, 24), 256, 0, stream>>>(Xb, Wqt, b_qkv, Qb, Kb, VtG);
  attn_kernel<<<dim3(128, 4), 512, 0, stream>>>(Qb, Kb, VtG, Ab);
  proj_gemm2<<<dim3(64, 8), 256, 0, stream>>>(Ab, Wpt, b_prj, out);
}

// Round 19
// 145.245 us; speedup vs baseline: 1.0276x; 1.0276x over previous
//
#include <hip/hip_runtime.h>
#include <hip/hip_bf16.h>

// Fused WindowAttention: x @ W_qkv + b -> MHA(16 heads, D=64) -> @ W_proj + b
// B=8, N=1024, C=1024. fp32 in/out; internal bf16 MFMA + fp32 accum.
//
// FINAL configuration (best measured, r17 = 145.4 us):
//   1. prep: X f32->bf16  +  W_qkv^T -> Wqt bf16  +  W_proj^T -> Wpt bf16
//   2. qkv_gemm2: 128x128 BK=64 swizzled, double-buffered counted-vmcnt
//   3. attn_kernel: 8 waves x 256 q-rows, swapped QK^T, log2 softmax,
//      defer-max, cvt_pk P-pack, XCD-local grid
//   4. proj_gemm2: same dbuf structure -> fp32 d_out

using bf16x8 = __attribute__((ext_vector_type(8))) short;
using f32x4  = __attribute__((ext_vector_type(4))) float;
using u16    = unsigned short;
using u16x8  = __attribute__((ext_vector_type(8))) unsigned short;
using u32x2  = __attribute__((ext_vector_type(2))) unsigned int;

__device__ __forceinline__ u16 f2bf(float f) {
  unsigned int u = __float_as_uint(f);
  u += 0x7FFFu + ((u >> 16) & 1u);   // RNE (finite inputs only)
  return (u16)(u >> 16);
}
__device__ __forceinline__ float bf2f(u16 h) {
  return __uint_as_float(((unsigned int)h) << 16);
}
__device__ __forceinline__ unsigned cvt_pk_bf16(float a, float b) {
  unsigned r;
  asm("v_cvt_pk_bf16_f32 %0, %1, %2" : "=v"(r) : "v"(a), "v"(b));
  return r;
}
__device__ __forceinline__ float fexp2(float x) {
#if __has_builtin(__builtin_amdgcn_exp2f)
  return __builtin_amdgcn_exp2f(x);
#else
  return exp2f(x);
#endif
}

__device__ __forceinline__ void gload16(const u16* g, u16* lbase, int lane) {
#if __has_builtin(__builtin_amdgcn_global_load_lds)
  __builtin_amdgcn_global_load_lds(
      (const __attribute__((address_space(1))) void*)g,
      (__attribute__((address_space(3))) void*)lbase, 16, 0, 0);
#else
  *(u16x8*)(lbase + (size_t)lane * 8) = *(const u16x8*)g;
#endif
}

// ---------------------------------------------------------------------------
// prep: block-range union {f32->bf16 convert, W_qkv^T, W_proj^T}.
// ---------------------------------------------------------------------------
__device__ __forceinline__ void transpose_tile(
    const float* __restrict__ W, u16* __restrict__ Wt, int K, int N,
    int n0, int k0, float (*T)[65], int t)
{
  const int r = t >> 4, c4 = (t & 15) * 4;
  #pragma unroll
  for (int i = 0; i < 4; ++i) {
    f32x4 v = *(const f32x4*)&W[(size_t)(k0 + r + i * 16) * N + n0 + c4];
    T[r + i * 16][c4 + 0] = v.x;
    T[r + i * 16][c4 + 1] = v.y;
    T[r + i * 16][c4 + 2] = v.z;
    T[r + i * 16][c4 + 3] = v.w;
  }
  __syncthreads();
  const int nr = t >> 2, cs = (t & 3) * 16;
  u16x8 h0, h1;
  #pragma unroll
  for (int j = 0; j < 8; ++j) h0[j] = f2bf(T[cs + j][nr]);
  #pragma unroll
  for (int j = 0; j < 8; ++j) h1[j] = f2bf(T[cs + 8 + j][nr]);
  u16* dst = Wt + (size_t)(n0 + nr) * K + k0 + cs;
  *(u16x8*)dst = h0;
  *(u16x8*)(dst + 8) = h1;
}

__global__ __launch_bounds__(256) void prep(
    const float* __restrict__ x, u16* __restrict__ Xb,
    const float* __restrict__ Wq, u16* __restrict__ Wqt,
    const float* __restrict__ Wp, u16* __restrict__ Wpt)
{
  __shared__ float T[64][65];
  const int bid = blockIdx.x, t = threadIdx.x;
  if (bid < 4096) {
    size_t i = ((size_t)bid * 256 + t) * 8;
    f32x4 a = *(const f32x4*)(x + i);
    f32x4 b = *(const f32x4*)(x + i + 4);
    u16x8 h = { f2bf(a.x), f2bf(a.y), f2bf(a.z), f2bf(a.w),
                f2bf(b.x), f2bf(b.y), f2bf(b.z), f2bf(b.w) };
    *(u16x8*)(Xb + i) = h;
  } else if (bid < 4864) {
    const int tb = bid - 4096;
    transpose_tile(Wq, Wqt, 1024, 3072, (tb % 48) * 64, (tb / 48) * 64, T, t);
  } else {
    const int tb = bid - 4864;
    transpose_tile(Wp, Wpt, 1024, 1024, (tb % 16) * 64, (tb / 16) * 64, T, t);
  }
}

// ---------------------------------------------------------------------------
// Double-buffered GEMM main loop: 128x128 tile, 4 waves (2x2), BK=64,
// 16 K-iters. Per iter: issue next tile's 8 gloads into buf^1, then
// s_waitcnt vmcnt(8) (current tile landed; next stays in flight), s_barrier,
// 2x{8 ds_read + 16 MFMA}, s_barrier. LDS [row][64] with 16B-slot XOR
// swizzle (slot ^= row&7) via pre-swizzled global source.
// ---------------------------------------------------------------------------
#define GEMM64_DBUF(ABASE, BBASE, AS, BS)                                     \
  const int tid = threadIdx.x;                                                \
  const int lane = tid & 63, wid = tid >> 6;                                  \
  const int wr = wid >> 1, wc = wid & 1;                                      \
  const int lg = lane >> 4, lc = lane & 15;                                   \
  const int row0 = blockIdx.x * 128, col0 = blockIdx.y * 128;                 \
  f32x4 acc[4][4];                                                            \
  _Pragma("unroll")                                                           \
  for (int m = 0; m < 4; ++m)                                                 \
    _Pragma("unroll")                                                         \
    for (int n = 0; n < 4; ++n) acc[m][n] = (f32x4){0.f, 0.f, 0.f, 0.f};      \
  const int srow = lane >> 3;                /* 0..7 */                       \
  const int sslot = (lane & 7) ^ srow;       /* pre-swizzled 16B slot */      \
  const u16* gA = (ABASE) + (size_t)(row0 + wid * 32 + srow) * 1024 + sslot * 8; \
  const u16* gB = (BBASE) + (size_t)(col0 + wid * 32 + srow) * 1024 + sslot * 8; \
  u16* lA = (AS) + wid * 2048;                                                \
  u16* lB = (BS) + wid * 2048;                                                \
  auto STAGE = [&](int tt) {                                                  \
    const int bo = (tt & 1) * 8192, ko = tt * 64;                             \
    _Pragma("unroll")                                                         \
    for (int c = 0; c < 4; ++c) {                                             \
      gload16(gA + (size_t)c * 8192 + ko, lA + bo + c * 512, lane);           \
      gload16(gB + (size_t)c * 8192 + ko, lB + bo + c * 512, lane);           \
    }                                                                         \
  };                                                                          \
  STAGE(0);                                                                   \
  const int xr = lc & 7;                                                      \
  const int sl0 = ((0 + lg) ^ xr) * 8, sl1 = ((4 + lg) ^ xr) * 8;             \
  const int arow = (wr * 64 + lc) * 64, brow = (wc * 64 + lc) * 64;           \
  for (int t = 0; t < 16; ++t) {                                              \
    if (t < 15) {                                                             \
      STAGE(t + 1);                                                           \
      asm volatile("s_waitcnt vmcnt(8)" ::: "memory");                        \
    } else {                                                                  \
      asm volatile("s_waitcnt vmcnt(0)" ::: "memory");                        \
    }                                                                         \
    __builtin_amdgcn_s_barrier();                                             \
    const int bo = (t & 1) * 8192;                                            \
    _Pragma("unroll")                                                         \
    for (int ks = 0; ks < 2; ++ks) {                                          \
      const int sl = ks ? sl1 : sl0;                                          \
      bf16x8 a[4], b[4];                                                      \
      _Pragma("unroll")                                                       \
      for (int m = 0; m < 4; ++m)                                             \
        a[m] = *(const bf16x8*)((AS) + bo + arow + m * 1024 + sl);            \
      _Pragma("unroll")                                                       \
      for (int n = 0; n < 4; ++n)                                             \
        b[n] = *(const bf16x8*)((BS) + bo + brow + n * 1024 + sl);            \
      __builtin_amdgcn_s_setprio(1);                                          \
      _Pragma("unroll")                                                       \
      for (int m = 0; m < 4; ++m)                                             \
        _Pragma("unroll")                                                     \
        for (int n = 0; n < 4; ++n)                                           \
          acc[m][n] = __builtin_amdgcn_mfma_f32_16x16x32_bf16(                \
              a[m], b[n], acc[m][n], 0, 0, 0);                                \
      __builtin_amdgcn_s_setprio(0);                                          \
    }                                                                         \
    __builtin_amdgcn_s_barrier();                                             \
  }

// ---------------------------------------------------------------------------
// QKV GEMM. Q,K -> [bh][n][64] scalar scatter; V tile -> LDS transpose ->
// coalesced V^T [bh][64][n]. LDS union {A+B dbuf 64KB | Tv 33.3KB}.
// ---------------------------------------------------------------------------
__global__ __launch_bounds__(256, 2) void qkv_gemm2(
    const u16* __restrict__ Xb, const u16* __restrict__ Wt,
    const float* __restrict__ bias,
    u16* __restrict__ Qb, u16* __restrict__ Kb, u16* __restrict__ VtG)
{
  __shared__ __align__(16) u16 SM[32768];   // 64 KB
  u16* As = SM;                 // 2 x 128*64
  u16* Bs = SM + 16384;         // 2 x 128*64
  u16* Tv = SM;                 // epilogue transpose buffer (union, 33.3KB)

  GEMM64_DBUF(Xb, Wt, As, Bs)

  const int which = col0 >> 10;   // block-uniform: 0=Q, 1=K, 2=V
  if (which == 2) {
    #pragma unroll
    for (int m = 0; m < 4; ++m) {
      #pragma unroll
      for (int n = 0; n < 4; ++n) {
        const int col = wc * 64 + n * 16 + lc;
        const float bv = bias[col0 + col];
        const int rrow = wr * 64 + m * 16 + lg * 4;
        #pragma unroll
        for (int r = 0; r < 4; ++r)
          Tv[(rrow + r) * 130 + col] = f2bf(acc[m][n][r] + bv);
      }
    }
    __syncthreads();
    const int c = tid >> 1, half = tid & 1;
    const int hh = c >> 6, d = c & 63;
    const int bb = row0 >> 10, nb = row0 & 1023;
    const int hbase = (col0 & 1023) >> 6;
    u16* vdst = VtG + ((size_t)(bb * 16 + hbase + hh) * 64 + d) * 1024
                + nb + half * 64;
    #pragma unroll
    for (int g = 0; g < 8; ++g) {
      u16x8 o;
      #pragma unroll
      for (int j = 0; j < 8; ++j)
        o[j] = Tv[(half * 64 + g * 8 + j) * 130 + c];
      *(u16x8*)(vdst + g * 8) = o;
    }
  } else {
    u16* dst = (which == 0) ? Qb : Kb;
    #pragma unroll
    for (int m = 0; m < 4; ++m) {
      #pragma unroll
      for (int n = 0; n < 4; ++n) {
        const int gc = col0 + wc * 64 + n * 16 + lc;
        const float bv = bias[gc];
        const int ci = gc & 1023, h = ci >> 6, d = ci & 63;
        const int gr0 = row0 + wr * 64 + m * 16 + lg * 4;
        const int bb = gr0 >> 10, nn0 = gr0 & 1023;
        #pragma unroll
        for (int r = 0; r < 4; ++r)
          dst[((size_t)(bb * 16 + h) * 1024 + nn0 + r) * 64 + d] =
              f2bf(acc[m][n][r] + bv);
      }
    }
  }
}

// ---------------------------------------------------------------------------
// Flash attention. Block = 256 q-rows of one (b,h); 8 waves x 32 rows.
// Grid (bh=128, qt=4): id%8 = bh%8 -> all q-tiles of a head on one XCD.
// Each wave stages 8 K-rows / 8 V^T d-rows per round (1 gload each,
// per-wave LDS stride 512 u16).
// ---------------------------------------------------------------------------
__global__ __launch_bounds__(512, 1) void attn_kernel(
    const u16* __restrict__ Q, const u16* __restrict__ K,
    const u16* __restrict__ Vt, u16* __restrict__ O)
{
  __shared__ __align__(16) u16 Ks[64 * 64];       // [key][d] swizzled, 8KB
  __shared__ __align__(16) u16 Vs[64 * 64];       // [d][key] swizzled, 8KB
  __shared__ __align__(16) u16 Pl[8 * 32 * 72];   // per-wave P, 36.9KB

  const int tid = threadIdx.x, lane = tid & 63, wid = tid >> 6;  // wid 0..7
  const int lg = lane >> 4, lc = lane & 15;
  const int bh = blockIdx.x;       // [0,128)
  const int qt = blockIdx.y;       // [0,4)
  const size_t base = (size_t)bh * 65536;
  const u16* Qp = Q + base;
  const u16* Kp = K + base;
  const u16* Vp = Vt + base;       // [64][1024]

  const float QSCALE = 0.125f * 1.44269504f;
  bf16x8 qf[2][2];
  #pragma unroll
  for (int f = 0; f < 2; ++f) {
    const u16* qsrc = Qp + (size_t)(qt * 256 + wid * 32 + f * 16 + lc) * 64 + lg * 8;
    #pragma unroll
    for (int ks = 0; ks < 2; ++ks) {
      u16x8 raw = *(const u16x8*)(qsrc + ks * 32);
      bf16x8 t;
      #pragma unroll
      for (int j = 0; j < 8; ++j) t[j] = (short)f2bf(bf2f(raw[j]) * QSCALE);
      qf[f][ks] = t;
    }
  }

  f32x4 o[2][4];
  #pragma unroll
  for (int f = 0; f < 2; ++f)
    #pragma unroll
    for (int d = 0; d < 4; ++d) o[f][d] = (f32x4){0.f, 0.f, 0.f, 0.f};
  float m_r[2] = {-1e30f, -1e30f};  // log2 domain
  float l_r[2] = {0.f, 0.f};        // per-lane partial row sums

  const int srow  = lane >> 3;               // 0..7
  const int sslot = (lane & 7) ^ srow;       // pre-swizzled 16B slot
  const u16* gK0 = Kp + (size_t)(wid * 8 + srow) * 64 + sslot * 8;
  const u16* gV0 = Vp + (size_t)(wid * 8 + srow) * 1024 + sslot * 8;
  u16* lK0 = Ks + wid * 512;
  u16* lV0 = Vs + wid * 512;

  const int xr = lc & 7;
  const int cof0 = ((0 + lg) ^ xr) * 8;
  const int cof1 = ((4 + lg) ^ xr) * 8;
  const int prow = (wid * 32 + lc) * 72;

  for (int kt = 0; kt < 16; ++kt) {
    gload16(gK0 + kt * 4096, lK0, lane);
    gload16(gV0 + kt * 64, lV0, lane);
    __syncthreads();

    f32x4 s[2][4];
    #pragma unroll
    for (int f = 0; f < 2; ++f)
      #pragma unroll
      for (int kb = 0; kb < 4; ++kb) s[f][kb] = (f32x4){0.f, 0.f, 0.f, 0.f};
    #pragma unroll
    for (int ks = 0; ks < 2; ++ks) {
      const int co = ks ? cof1 : cof0;
      #pragma unroll
      for (int kb = 0; kb < 4; ++kb) {
        bf16x8 kfr = *(const bf16x8*)(Ks + (kb * 16 + lc) * 64 + co);
        s[0][kb] = __builtin_amdgcn_mfma_f32_16x16x32_bf16(kfr, qf[0][ks], s[0][kb], 0, 0, 0);
        s[1][kb] = __builtin_amdgcn_mfma_f32_16x16x32_bf16(kfr, qf[1][ks], s[1][kb], 0, 0, 0);
      }
    }

    #pragma unroll
    for (int f = 0; f < 2; ++f) {
      f32x4 t01, t23;
      #pragma unroll
      for (int c = 0; c < 4; ++c) {
        t01[c] = fmaxf(s[f][0][c], s[f][1][c]);
        t23[c] = fmaxf(s[f][2][c], s[f][3][c]);
      }
      float t = fmaxf(fmaxf(fmaxf(t01[0], t01[1]), fmaxf(t01[2], t01[3])),
                      fmaxf(fmaxf(t23[0], t23[1]), fmaxf(t23[2], t23[3])));
      t = fmaxf(t, __shfl_xor(t, 16));
      t = fmaxf(t, __shfl_xor(t, 32));

      if (!__all((t - m_r[f]) <= 11.5f)) {          // max grew: rescale
        float nm = fmaxf(m_r[f], t);
        float sc = fexp2(m_r[f] - nm);
        m_r[f] = nm;
        l_r[f] *= sc;
        #pragma unroll
        for (int r = 0; r < 4; ++r) {
          float scr = __shfl(sc, lg * 4 + r, 16);
          #pragma unroll
          for (int d = 0; d < 4; ++d) o[f][d][r] *= scr;
        }
      }

      float lsum = 0.f;
      #pragma unroll
      for (int kb = 0; kb < 4; ++kb) {
        f32x4 p;
        #pragma unroll
        for (int c = 0; c < 4; ++c) {
          p[c] = fexp2(s[f][kb][c] - m_r[f]);
          lsum += p[c];
        }
        u32x2 w = { cvt_pk_bf16(p[0], p[1]), cvt_pk_bf16(p[2], p[3]) };
        *(u32x2*)(Pl + prow + f * 1152 + kb * 16 + lg * 4) = w;
      }
      l_r[f] += lsum;   // partial; cross-lane reduce in epilogue
    }

    asm volatile("s_waitcnt lgkmcnt(0)" ::: "memory");
    __builtin_amdgcn_sched_barrier(0);

    bf16x8 pa[2][2];
    #pragma unroll
    for (int f = 0; f < 2; ++f)
      #pragma unroll
      for (int ks = 0; ks < 2; ++ks)
        pa[f][ks] = *(const bf16x8*)(Pl + prow + f * 1152 + ks * 32 + lg * 8);
    #pragma unroll
    for (int d = 0; d < 4; ++d) {
      #pragma unroll
      for (int ks = 0; ks < 2; ++ks) {
        const int co = ks ? cof1 : cof0;
        bf16x8 vfr = *(const bf16x8*)(Vs + (d * 16 + lc) * 64 + co);
        o[0][d] = __builtin_amdgcn_mfma_f32_16x16x32_bf16(pa[0][ks], vfr, o[0][d], 0, 0, 0);
        o[1][d] = __builtin_amdgcn_mfma_f32_16x16x32_bf16(pa[1][ks], vfr, o[1][d], 0, 0, 0);
      }
    }
    __syncthreads();
  }

  const int b = bh >> 4, h = bh & 15;
  #pragma unroll
  for (int f = 0; f < 2; ++f) {
    float t = l_r[f];
    t += __shfl_xor(t, 16);
    t += __shfl_xor(t, 32);
    float linv = 1.0f / t;
    #pragma unroll
    for (int r = 0; r < 4; ++r) {
      float li = __shfl(linv, lg * 4 + r, 16);
      int n = qt * 256 + wid * 32 + f * 16 + lg * 4 + r;
      u16* dst = O + ((size_t)b * 1024 + n) * 1024 + h * 64 + lc;
      #pragma unroll
      for (int d = 0; d < 4; ++d) dst[d * 16] = f2bf(o[f][d][r] * li);
    }
  }
}

// ---------------------------------------------------------------------------
// Projection GEMM (dbuf structure).
// ---------------------------------------------------------------------------
__global__ __launch_bounds__(256, 2) void proj_gemm2(
    const u16* __restrict__ Ab, const u16* __restrict__ Wt,
    const float* __restrict__ bias, float* __restrict__ Out)
{
  __shared__ __align__(16) u16 As[2 * 128 * 64];
  __shared__ __align__(16) u16 Bs[2 * 128 * 64];

  GEMM64_DBUF(Ab, Wt, As, Bs)

  #pragma unroll
  for (int m = 0; m < 4; ++m) {
    #pragma unroll
    for (int n = 0; n < 4; ++n) {
      #pragma unroll
      for (int r = 0; r < 4; ++r) {
        int gr = row0 + wr * 64 + m * 16 + lg * 4 + r;
        int gc = col0 + wc * 64 + n * 16 + lc;
        Out[(size_t)gr * 1024 + gc] = acc[m][n][r] + bias[gc];
      }
    }
  }
}

// ---------------------------------------------------------------------------
extern "C" void kernel_launch(void* const* d_in, const int* in_sizes, int n_in,
                              void* d_out, int out_size, void* d_ws, size_t ws_size,
                              hipStream_t stream) {
  const float* x     = (const float*)d_in[0];
  const float* W_qkv = (const float*)d_in[1];
  const float* b_qkv = (const float*)d_in[2];
  const float* W_prj = (const float*)d_in[3];
  const float* b_prj = (const float*)d_in[4];
  float* out = (float*)d_out;

  const size_t SEG = (size_t)8192 * 1024;   // 8388608 elems (u16)
  char* ws = (char*)d_ws;                   // needs ~42 MiB
  u16* Xb  = (u16*)ws;                      // dead after qkv
  u16* Ab  = Xb;                            // alias: attn output
  u16* VtG = (u16*)(ws + SEG * 2);          // V^T [bh][64][1024]
  u16* Wqt = (u16*)(ws + SEG * 4);
  u16* Wpt = Wqt + (size_t)3072 * 1024;
  u16* Qb  = (u16*)d_out;                   // d_out as scratch
  u16* Kb  = Qb + SEG;

  prep<<<5120, 256, 0, stream>>>(x, Xb, W_qkv, Wqt, W_prj, Wpt);
  qkv_gemm2<<<dim3(64, 24), 256, 0, stream>>>(Xb, Wqt, b_qkv, Qb, Kb, VtG);
  attn_kernel<<<dim3(128, 4), 512, 0, stream>>>(Qb, Kb, VtG, Ab);
  proj_gemm2<<<dim3(64, 8), 256, 0, stream>>>(Ab, Wpt, b_prj, out);
}